// Round 17
// baseline (98.397 us; speedup 1.0000x reference)
//
#include <hip/hip_runtime.h>
#include <hip/hip_bf16.h>
#include <math.h>

#define DIM 768
#define NH 12
#define DH 64
#define SEQ 2048
#define BATCH 2
#define TOK (BATCH*SEQ)   // 4096
#define QKVN (3*DIM)      // 2304

typedef __attribute__((ext_vector_type(8))) short bf16x8;
typedef __attribute__((ext_vector_type(4))) float f32x4;
typedef __attribute__((ext_vector_type(2))) unsigned int u32x2;
typedef unsigned short u16;

#define VM0 asm volatile("s_waitcnt vmcnt(0)" ::: "memory")
#define VM3 asm volatile("s_waitcnt vmcnt(3)" ::: "memory")
#define VM4 asm volatile("s_waitcnt vmcnt(4)" ::: "memory")
#define LGKM0 asm volatile("s_waitcnt lgkmcnt(0)" ::: "memory")
#define BAR() __builtin_amdgcn_s_barrier()

__device__ inline u16 f2bf(float f) {
  union { float f; unsigned u; } v; v.f = f;
  unsigned u = v.u;
  u += 0x7fffu + ((u >> 16) & 1u);   // round-to-nearest-even
  return (u16)(u >> 16);
}

__device__ inline int pkbf(float a, float b) {   // packed bf16 pair (RNE)
  __hip_bfloat162 h = __float22bfloat162_rn(make_float2(a, b));
  int r; __builtin_memcpy(&r, &h, 4); return r;
}

// One launch: convert x, qkv_w, proj_w to bf16 AND build the rope cos/sin table.
__global__ void conv_all(const float* __restrict__ a, u16* __restrict__ ao, int na4,
                         const float* __restrict__ b, u16* __restrict__ bo, int nb4,
                         const float* __restrict__ c, u16* __restrict__ co, int nc4,
                         const float* __restrict__ pos, float2* __restrict__ tab) {
  int i4 = blockIdx.x * blockDim.x + threadIdx.x;
  const int nconv = na4 + nb4 + nc4;
  if (i4 < nconv) {
    const float* src; u16* dst; int off;
    if (i4 < na4)            { src = a; dst = ao; off = i4; }
    else if (i4 < na4 + nb4) { src = b; dst = bo; off = i4 - na4; }
    else                     { src = c; dst = co; off = i4 - na4 - nb4; }
    float4 v = ((const float4*)src)[off];
    ushort4 o;
    o.x = f2bf(v.x); o.y = f2bf(v.y); o.z = f2bf(v.z); o.w = f2bf(v.w);
    ((ushort4*)dst)[off] = o;
    return;
  }
  int e = i4 - nconv;                 // rope table: 4096*32 entries
  if (e >= TOK * 32) return;
  int t = e >> 5, p = e & 31;
  float cs = 1.f, sn = 0.f;
  if (p < 30) {
    int axis = p / 10, fi = p % 10;
    float freq = exp2f(-(float)fi * 1.3287712379549449f); // log2(10000)/10
    float ang = pos[t * 3 + axis] * freq;
    cs = cosf(ang); sn = sinf(ang);
  }
  tab[e] = make_float2(cs, sn);
}

#define GLL(g, s) __builtin_amdgcn_global_load_lds((const __attribute__((address_space(1))) void*)(g), (__attribute__((address_space(3))) void*)(s), 16, 0, 0)

// Proj GEMM: C = A * W^T + bias. 64x64 tile, BK=64, XOR-swizzled LDS.
__global__ __launch_bounds__(256, 4) void gemm64(
    const u16* __restrict__ A, const u16* __restrict__ W,
    float* __restrict__ C, const float* __restrict__ bias,
    int M, int Nn, int K)
{
  __shared__ u16 As[2][64 * 64];
  __shared__ u16 Bs[2][64 * 64];
  const int t = threadIdx.x;
  const int w = t >> 6, l = t & 63;
  const int lr = l & 15, lg = l >> 4;
  const int wr = w >> 1, wc = w & 1;
  const int m0 = blockIdx.x * 64;
  const int n0 = blockIdx.y * 64;
  f32x4 acc[2][2] = {};
  const int srow = t >> 3;                      // 0..31
  const int scol = (((t & 7) ^ (srow & 7)) * 8);
  const u16* aSrc = A + (size_t)(m0 + srow) * K + scol;
  const u16* bSrc = W + (size_t)(n0 + srow) * K + scol;
  const size_t r32 = (size_t)32 * K;
  const int sw = lr & 7;
  const int NT = K / 64;

  GLL(aSrc,       &As[0][w * 512]);
  GLL(aSrc + r32, &As[0][2048 + w * 512]);
  GLL(bSrc,       &Bs[0][w * 512]);
  GLL(bSrc + r32, &Bs[0][2048 + w * 512]);

  for (int kt = 0; kt < NT; ++kt) {
    const int cur = kt & 1;
    if (kt + 1 < NT) {
      const int k0 = (kt + 1) * 64;
      GLL(aSrc + k0,       &As[cur ^ 1][w * 512]);
      GLL(aSrc + r32 + k0, &As[cur ^ 1][2048 + w * 512]);
      GLL(bSrc + k0,       &Bs[cur ^ 1][w * 512]);
      GLL(bSrc + r32 + k0, &Bs[cur ^ 1][2048 + w * 512]);
      VM4;
    } else {
      VM0;
    }
    BAR();
#pragma unroll
    for (int kk = 0; kk < 2; ++kk) {
      bf16x8 af[2], bff[2];
#pragma unroll
      for (int mi = 0; mi < 2; ++mi)
        af[mi] = *(const bf16x8*)(&As[cur][0] + (wr * 32 + mi * 16 + lr) * 64 + (((kk * 4 + lg) ^ sw) * 8));
#pragma unroll
      for (int ni = 0; ni < 2; ++ni)
        bff[ni] = *(const bf16x8*)(&Bs[cur][0] + (wc * 32 + ni * 16 + lr) * 64 + (((kk * 4 + lg) ^ sw) * 8));
#pragma unroll
      for (int mi = 0; mi < 2; ++mi)
#pragma unroll
        for (int ni = 0; ni < 2; ++ni)
          acc[mi][ni] = __builtin_amdgcn_mfma_f32_16x16x32_bf16(af[mi], bff[ni], acc[mi][ni], 0, 0, 0);
    }
    LGKM0;
    BAR();
  }

#pragma unroll
  for (int mi = 0; mi < 2; ++mi)
#pragma unroll
    for (int ni = 0; ni < 2; ++ni)
#pragma unroll
      for (int r = 0; r < 4; ++r) {
        int row = m0 + wr * 32 + mi * 16 + lg * 4 + r;
        int col = n0 + wc * 32 + ni * 16 + lr;
        C[(size_t)row * Nn + col] = acc[mi][ni][r] + bias[col];
      }
}

// QKV GEMM + fused RMSNorm/RoPE/layout. 128M x 64N tile, 8 waves of 16x64.
__global__ __launch_bounds__(512, 6) void gemm_qkv(
    const u16* __restrict__ A, const u16* __restrict__ W,
    const float* __restrict__ qn_w, const float* __restrict__ kn_w,
    const float2* __restrict__ tab,
    u16* __restrict__ Qb, u16* __restrict__ Kb, u16* __restrict__ Vtb)
{
  __shared__ u16 As[2][128 * 64];   // 16KB
  __shared__ u16 Bs[2][64 * 64];    // 8KB
  const int K = DIM;
  const int t = threadIdx.x;
  const int w = t >> 6, l = t & 63;
  const int lr = l & 15, lg = l >> 4;
  const int m0 = blockIdx.x * 128;
  const int n0 = blockIdx.y * 64;
  f32x4 acc[4] = {};
  const int srow = t >> 3;                      // 0..63
  const int scol = (((t & 7) ^ (srow & 7)) * 8);
  const u16* aSrc = A + (size_t)(m0 + srow) * K + scol;
  const u16* bSrc = W + (size_t)(n0 + srow) * K + scol;
  const size_t r64 = (size_t)64 * K;
  const int sw = lr & 7;
  const int NT = K / 64;

  GLL(aSrc,       &As[0][w * 512]);
  GLL(aSrc + r64, &As[0][4096 + w * 512]);
  GLL(bSrc,       &Bs[0][w * 512]);

  for (int kt = 0; kt < NT; ++kt) {
    const int cur = kt & 1;
    if (kt + 1 < NT) {
      const int k0 = (kt + 1) * 64;
      GLL(aSrc + k0,       &As[cur ^ 1][w * 512]);
      GLL(aSrc + r64 + k0, &As[cur ^ 1][4096 + w * 512]);
      GLL(bSrc + k0,       &Bs[cur ^ 1][w * 512]);
      VM3;
    } else {
      VM0;
    }
    BAR();
#pragma unroll
    for (int kk = 0; kk < 2; ++kk) {
      bf16x8 af = *(const bf16x8*)(&As[cur][0] + (w * 16 + lr) * 64 + (((kk * 4 + lg) ^ sw) * 8));
      bf16x8 bff[4];
#pragma unroll
      for (int ni = 0; ni < 4; ++ni)
        bff[ni] = *(const bf16x8*)(&Bs[cur][0] + (ni * 16 + lr) * 64 + (((kk * 4 + lg) ^ sw) * 8));
#pragma unroll
      for (int ni = 0; ni < 4; ++ni)
        acc[ni] = __builtin_amdgcn_mfma_f32_16x16x32_bf16(af, bff[ni], acc[ni], 0, 0, 0);
    }
    LGKM0;
    BAR();
  }

  // ---- fused epilogue ----
  const int chunk = n0 >> 6;               // 0..35 over [3 types][12 heads]
  const int tt = chunk / 12;               // 0=q 1=k 2=v
  const int h  = chunk % 12;
  const int bB = m0 >> 11;                 // batch (block-const)
  const int bh = bB * NH + h;

  if (tt == 2) {
    const int nbase = (m0 + w * 16 + lg * 4) & 2047;
#pragma unroll
    for (int ni = 0; ni < 4; ++ni) {
      const int d = ni * 16 + lr;
      ushort4 o;
      o.x = f2bf(acc[ni][0]); o.y = f2bf(acc[ni][1]);
      o.z = f2bf(acc[ni][2]); o.w = f2bf(acc[ni][3]);
      *(ushort4*)(Vtb + ((size_t)bh * DH + d) * SEQ + nbase) = o;
    }
  } else {
    const float* wv = (tt == 0 ? qn_w : kn_w);
    const float qs = (tt == 0 ? 0.125f * 1.4426950408889634f : 1.f);
    float wgt[4];
#pragma unroll
    for (int ni = 0; ni < 4; ++ni) wgt[ni] = wv[ni * 16 + lr];
    u16* outp = (tt == 0 ? Qb : Kb) + (size_t)bh * SEQ * DH;
#pragma unroll
    for (int r = 0; r < 4; ++r) {
      float ss = 0.f;
#pragma unroll
      for (int ni = 0; ni < 4; ++ni) ss += acc[ni][r] * acc[ni][r];
      ss += __shfl_xor(ss, 1, 64);
      ss += __shfl_xor(ss, 2, 64);
      ss += __shfl_xor(ss, 4, 64);
      ss += __shfl_xor(ss, 8, 64);
      const float rms = rsqrtf(ss * (1.f / 64.f) + 1e-6f);
      const int trow = m0 + w * 16 + lg * 4 + r;
      const float2* tl = tab + trow * 32;
      u16* rowp = outp + (size_t)(trow & 2047) * DH;
#pragma unroll
      for (int ni = 0; ni < 4; ++ni) {
        const int d = ni * 16 + lr;
        float v = acc[ni][r] * rms * wgt[ni];
        float vp = __shfl_xor(v, 1, 64);
        float2 cssn = tl[ni * 8 + (lr >> 1)];
        float sgn = (d & 1) ? cssn.y : -cssn.y;
        rowp[d] = f2bf((v * cssn.x + vp * sgn) * qs);
      }
    }
  }
}

// Flash attention v8: KV-split. Grid 1536 = (bh, q-tile, kvh in {0,1}); each
// block = v7 structure (4 waves x 16q, shared KV tile, 32KB LDS) over 16 KV
// tiles of its half. Unshifted-softmax partials are additive: block writes
// fp32 (oacc, lsum) partials; combine kernel sums halves and normalizes.
// 1536 blocks -> 6/CU available, 5 co-resident (LDS-capped) vs 3 before.
__global__ __launch_bounds__(256, 5) void attn(
    const u16* __restrict__ Qb, const u16* __restrict__ Kb,
    const u16* __restrict__ Vtb, float* __restrict__ Opart,
    float* __restrict__ Lpart)
{
  __shared__ u16 Kd[2][64 * 64];   // 16KB
  __shared__ u16 Vd[2][64 * 64];   // 16KB
  const int tid = threadIdx.x;
  const int w = tid >> 6, l = tid & 63;
  const int lr = l & 15, lg = l >> 4;
  const int wg = blockIdx.x;
  const int swz = (wg & 7) * 192 + (wg >> 3);  // bijective: 1536 = 8*192
  const int bh = swz >> 6;                      // 0..23
  const int rest = swz & 63;
  const int q0 = (rest >> 1) * 64;              // 32 q-tiles
  const int kvh = rest & 1;                     // KV half
  const u16* Qp = Qb + (size_t)bh * SEQ * DH;
  const u16* Kp = Kb + (size_t)bh * SEQ * DH;
  const u16* Vp = Vtb + (size_t)bh * DH * SEQ;

  const int qrow = q0 + w * 16 + lr;
  const bf16x8 bq0 = *(const bf16x8*)(Qp + (size_t)qrow * DH + 8 * lg);
  const bf16x8 bq1 = *(const bf16x8*)(Qp + (size_t)qrow * DH + 32 + 8 * lg);

  const int srow = tid >> 3;                  // 0..31
  const int sc16 = (tid & 7) ^ (srow & 7);
  const u16* kSrc = Kp + (size_t)srow * DH + sc16 * 8;    // + i*4096
  const u16* vSrc = Vp + (size_t)srow * SEQ + sc16 * 8;   // + i*64

  const int frow = (lr & 3) | ((lr & 4) << 1) | ((lr & 8) >> 1);
  const int ksw = frow & 7;
  const int vsw = lr & 7;

  bf16x8 vone;
#pragma unroll
  for (int j = 0; j < 8; ++j) vone[j] = (short)0x3F80;

  f32x4 oacc[4] = {};
  f32x4 lacc = {};

  const int i0 = kvh * 16;
  // prologue: stage tile i0 (K and V)
  GLL(kSrc + (size_t)i0 * 4096,         &Kd[0][w * 512]);
  GLL(kSrc + (size_t)i0 * 4096 + 2048,  &Kd[0][w * 512 + 2048]);
  GLL(vSrc + (size_t)i0 * 64,           &Vd[0][w * 512]);
  GLL(vSrc + (size_t)i0 * 64 + 65536,   &Vd[0][w * 512 + 2048]);
  VM0;
  BAR();

  for (int ii = 0; ii < 16; ++ii) {
    const int i = i0 + ii;
    const int cur = ii & 1;
    if (ii + 1 < 16) {   // K(i+1), V(i+1) into [cur^1]; flight = this whole iter
      const size_t ko = (size_t)(i + 1) * 4096;
      const size_t vo = (size_t)(i + 1) * 64;
      GLL(kSrc + ko,         &Kd[cur ^ 1][w * 512]);
      GLL(kSrc + ko + 2048,  &Kd[cur ^ 1][w * 512 + 2048]);
      GLL(vSrc + vo,         &Vd[cur ^ 1][w * 512]);
      GLL(vSrc + vo + 65536, &Vd[cur ^ 1][w * 512 + 2048]);
    }
    const u16* Kt = &Kd[cur][0];
    const u16* Vt = &Vd[cur][0];

    // QK: 8 MFMA
    f32x4 pacc[4] = {};
    __builtin_amdgcn_s_setprio(1);
#pragma unroll
    for (int c = 0; c < 4; ++c) {
      const int rbase = (16 * c + frow) * 64;
      bf16x8 ka = *(const bf16x8*)(Kt + rbase + ((lg ^ ksw) * 8));
      bf16x8 kb = *(const bf16x8*)(Kt + rbase + (((4 + lg) ^ ksw) * 8));
      pacc[c] = __builtin_amdgcn_mfma_f32_16x16x32_bf16(ka, bq0, pacc[c], 0, 0, 0);
      pacc[c] = __builtin_amdgcn_mfma_f32_16x16x32_bf16(kb, bq1, pacc[c], 0, 0, 0);
    }
    __builtin_amdgcn_s_setprio(0);

    // softmax in-register (unshifted exp2)
    union { unsigned d[4]; bf16x8 v; } pu[2];
#pragma unroll
    for (int g = 0; g < 2; ++g) {
      const int clo = 2 * g, chi = 2 * g + 1;
      float e[8];
#pragma unroll
      for (int r = 0; r < 4; ++r) {
        e[r]     = __builtin_amdgcn_exp2f(pacc[clo][r]);
        e[4 + r] = __builtin_amdgcn_exp2f(pacc[chi][r]);
      }
      u32x2 a0 = __builtin_amdgcn_permlane32_swap((unsigned)pkbf(e[0], e[1]),
                                                  (unsigned)pkbf(e[4], e[5]), false, false);
      u32x2 a1 = __builtin_amdgcn_permlane32_swap((unsigned)pkbf(e[2], e[3]),
                                                  (unsigned)pkbf(e[6], e[7]), false, false);
      pu[g].d[0] = a0[0]; pu[g].d[1] = a1[0]; pu[g].d[2] = a0[1]; pu[g].d[3] = a1[1];
    }

    // PV: 10 MFMA (V(i) resident since previous barrier)
    __builtin_amdgcn_s_setprio(1);
#pragma unroll
    for (int g = 0; g < 2; ++g) {
#pragma unroll
      for (int dt = 0; dt < 4; ++dt) {
        bf16x8 va = *(const bf16x8*)(Vt + (16 * dt + lr) * 64 + (((4 * g + lg) ^ vsw) * 8));
        oacc[dt] = __builtin_amdgcn_mfma_f32_16x16x32_bf16(va, pu[g].v, oacc[dt], 0, 0, 0);
      }
      lacc = __builtin_amdgcn_mfma_f32_16x16x32_bf16(vone, pu[g].v, lacc, 0, 0, 0);
    }
    __builtin_amdgcn_s_setprio(0);

    if (ii + 1 < 16) {
      LGKM0;  // my reads of Kd[cur]/Vd[cur] done
      VM0;    // my K(i+1)/V(i+1) GLLs landed
      BAR();  // tile i+1 visible block-wide; buffers [cur] free
    }
  }

  // epilogue: fp32 partials. Lane holds o[d][q]: q=lr, d=16dt+4lg+r.
  const int q = q0 + w * 16 + lr;
  float* Op = Opart + ((size_t)(kvh * 24 + bh) * SEQ + q) * 64;
#pragma unroll
  for (int dt = 0; dt < 4; ++dt)
    *(f32x4*)(Op + 16 * dt + 4 * lg) = oacc[dt];
  if (lg == 0)
    Lpart[(size_t)(kvh * 24 + bh) * SEQ + q] = lacc[0];
}

// Combine: o = (O0+O1)/(L0+L1), write bf16 Ob. One 64-lane row per wave.
__global__ __launch_bounds__(256) void combine(
    const float* __restrict__ Opart, const float* __restrict__ Lpart,
    u16* __restrict__ Ob)
{
  const int row = blockIdx.x * 4 + (threadIdx.x >> 6);   // bh*2048 + q
  const int d = threadIdx.x & 63;
  const size_t half = (size_t)24 * SEQ;
  const float o0 = Opart[(size_t)row * 64 + d];
  const float o1 = Opart[(half + row) * 64 + d];
  const float inv = 1.f / (Lpart[row] + Lpart[half + row]);
  const int bh = row >> 11, q = row & 2047;
  const int b = bh / NH, h = bh % NH;
  Ob[((size_t)(b * SEQ + q)) * DIM + h * DH + d] = f2bf((o0 + o1) * inv);
}

extern "C" void kernel_launch(void* const* d_in, const int* in_sizes, int n_in,
                              void* d_out, int out_size, void* d_ws, size_t ws_size,
                              hipStream_t stream) {
  const float* x      = (const float*)d_in[0];
  const float* pos    = (const float*)d_in[1];
  const float* qkv_w  = (const float*)d_in[2];
  const float* proj_w = (const float*)d_in[3];
  const float* proj_b = (const float*)d_in[4];
  const float* qn_w   = (const float*)d_in[5];
  const float* kn_w   = (const float*)d_in[6];
  char* ws = (char*)d_ws;
  u16*    xb    = (u16*)(ws + 0);          // 6291456
  u16*    wqkv  = (u16*)(ws + 6291456);    // 3538944
  u16*    wproj = (u16*)(ws + 9830400);    // 1179648
  float2* tab   = (float2*)(ws + 11010048);// 1048576
  u16*    Qb    = (u16*)(ws + 12058624);   // 6291456
  u16*    Kb    = (u16*)(ws + 18350080);   // 6291456
  u16*    Vtb   = (u16*)(ws + 24641536);   // 6291456
  u16*    Ob    = (u16*)(ws + 30932992);   // 6291456 -> 37224448
  float*  Opart = (float*)(ws + 37224448); // 2*24*2048*64*4 = 25165824
  float*  Lpart = (float*)(ws + 62390272); // 2*24*2048*4 = 393216 -> 62783488
  float* out = (float*)d_out;

  const int na4 = TOK * DIM / 4, nb4 = QKVN * DIM / 4, nc4 = DIM * DIM / 4;
  const int ntot = na4 + nb4 + nc4 + TOK * 32;
  conv_all<<<(ntot + 255) / 256, 256, 0, stream>>>(
      x, xb, na4, qkv_w, wqkv, nb4, proj_w, wproj, nc4, pos, tab);

  dim3 g1(TOK / 128, QKVN / 64);
  gemm_qkv<<<g1, 512, 0, stream>>>(xb, wqkv, qn_w, kn_w, tab, Qb, Kb, Vtb);

  attn<<<SEQ / 64 * BATCH * NH * 2, 256, 0, stream>>>(Qb, Kb, Vtb, Opart, Lpart);

  combine<<<BATCH * NH * SEQ / 4, 256, 0, stream>>>(Opart, Lpart, Ob);

  dim3 g3(TOK / 64, DIM / 64);
  gemm64<<<g3, 256, 0, stream>>>(Ob, wproj, out, proj_b, TOK, DIM, DIM);
}

// Round 18
// 87.117 us; speedup vs baseline: 1.1295x; 1.1295x over previous
//
#include <hip/hip_runtime.h>
#include <hip/hip_bf16.h>
#include <math.h>

#define DIM 768
#define NH 12
#define DH 64
#define SEQ 2048
#define BATCH 2
#define TOK (BATCH*SEQ)   // 4096
#define QKVN (3*DIM)      // 2304

typedef __attribute__((ext_vector_type(8))) short bf16x8;
typedef __attribute__((ext_vector_type(4))) float f32x4;
typedef __attribute__((ext_vector_type(2))) unsigned int u32x2;
typedef unsigned short u16;

#define VM0 asm volatile("s_waitcnt vmcnt(0)" ::: "memory")
#define VM3 asm volatile("s_waitcnt vmcnt(3)" ::: "memory")
#define VM4 asm volatile("s_waitcnt vmcnt(4)" ::: "memory")
#define LGKM0 asm volatile("s_waitcnt lgkmcnt(0)" ::: "memory")
#define BAR() __builtin_amdgcn_s_barrier()

__device__ inline u16 f2bf(float f) {
  union { float f; unsigned u; } v; v.f = f;
  unsigned u = v.u;
  u += 0x7fffu + ((u >> 16) & 1u);   // round-to-nearest-even
  return (u16)(u >> 16);
}

__device__ inline int pkbf(float a, float b) {   // packed bf16 pair (RNE)
  __hip_bfloat162 h = __float22bfloat162_rn(make_float2(a, b));
  int r; __builtin_memcpy(&r, &h, 4); return r;
}

// One launch: convert x, qkv_w, proj_w to bf16 AND build the rope cos/sin table.
__global__ void conv_all(const float* __restrict__ a, u16* __restrict__ ao, int na4,
                         const float* __restrict__ b, u16* __restrict__ bo, int nb4,
                         const float* __restrict__ c, u16* __restrict__ co, int nc4,
                         const float* __restrict__ pos, float2* __restrict__ tab) {
  int i4 = blockIdx.x * blockDim.x + threadIdx.x;
  const int nconv = na4 + nb4 + nc4;
  if (i4 < nconv) {
    const float* src; u16* dst; int off;
    if (i4 < na4)            { src = a; dst = ao; off = i4; }
    else if (i4 < na4 + nb4) { src = b; dst = bo; off = i4 - na4; }
    else                     { src = c; dst = co; off = i4 - na4 - nb4; }
    float4 v = ((const float4*)src)[off];
    ushort4 o;
    o.x = f2bf(v.x); o.y = f2bf(v.y); o.z = f2bf(v.z); o.w = f2bf(v.w);
    ((ushort4*)dst)[off] = o;
    return;
  }
  int e = i4 - nconv;                 // rope table: 4096*32 entries
  if (e >= TOK * 32) return;
  int t = e >> 5, p = e & 31;
  float cs = 1.f, sn = 0.f;
  if (p < 30) {
    int axis = p / 10, fi = p % 10;
    float freq = exp2f(-(float)fi * 1.3287712379549449f); // log2(10000)/10
    float ang = pos[t * 3 + axis] * freq;
    cs = cosf(ang); sn = sinf(ang);
  }
  tab[e] = make_float2(cs, sn);
}

#define GLL(g, s) __builtin_amdgcn_global_load_lds((const __attribute__((address_space(1))) void*)(g), (__attribute__((address_space(3))) void*)(s), 16, 0, 0)

// Proj GEMM: C = A * W^T + bias. 64x64 tile, BK=64, XOR-swizzled LDS.
__global__ __launch_bounds__(256, 4) void gemm64(
    const u16* __restrict__ A, const u16* __restrict__ W,
    float* __restrict__ C, const float* __restrict__ bias,
    int M, int Nn, int K)
{
  __shared__ u16 As[2][64 * 64];
  __shared__ u16 Bs[2][64 * 64];
  const int t = threadIdx.x;
  const int w = t >> 6, l = t & 63;
  const int lr = l & 15, lg = l >> 4;
  const int wr = w >> 1, wc = w & 1;
  const int m0 = blockIdx.x * 64;
  const int n0 = blockIdx.y * 64;
  f32x4 acc[2][2] = {};
  const int srow = t >> 3;                      // 0..31
  const int scol = (((t & 7) ^ (srow & 7)) * 8);
  const u16* aSrc = A + (size_t)(m0 + srow) * K + scol;
  const u16* bSrc = W + (size_t)(n0 + srow) * K + scol;
  const size_t r32 = (size_t)32 * K;
  const int sw = lr & 7;
  const int NT = K / 64;

  GLL(aSrc,       &As[0][w * 512]);
  GLL(aSrc + r32, &As[0][2048 + w * 512]);
  GLL(bSrc,       &Bs[0][w * 512]);
  GLL(bSrc + r32, &Bs[0][2048 + w * 512]);

  for (int kt = 0; kt < NT; ++kt) {
    const int cur = kt & 1;
    if (kt + 1 < NT) {
      const int k0 = (kt + 1) * 64;
      GLL(aSrc + k0,       &As[cur ^ 1][w * 512]);
      GLL(aSrc + r32 + k0, &As[cur ^ 1][2048 + w * 512]);
      GLL(bSrc + k0,       &Bs[cur ^ 1][w * 512]);
      GLL(bSrc + r32 + k0, &Bs[cur ^ 1][2048 + w * 512]);
      VM4;
    } else {
      VM0;
    }
    BAR();
#pragma unroll
    for (int kk = 0; kk < 2; ++kk) {
      bf16x8 af[2], bff[2];
#pragma unroll
      for (int mi = 0; mi < 2; ++mi)
        af[mi] = *(const bf16x8*)(&As[cur][0] + (wr * 32 + mi * 16 + lr) * 64 + (((kk * 4 + lg) ^ sw) * 8));
#pragma unroll
      for (int ni = 0; ni < 2; ++ni)
        bff[ni] = *(const bf16x8*)(&Bs[cur][0] + (wc * 32 + ni * 16 + lr) * 64 + (((kk * 4 + lg) ^ sw) * 8));
#pragma unroll
      for (int mi = 0; mi < 2; ++mi)
#pragma unroll
        for (int ni = 0; ni < 2; ++ni)
          acc[mi][ni] = __builtin_amdgcn_mfma_f32_16x16x32_bf16(af[mi], bff[ni], acc[mi][ni], 0, 0, 0);
    }
    LGKM0;
    BAR();
  }

#pragma unroll
  for (int mi = 0; mi < 2; ++mi)
#pragma unroll
    for (int ni = 0; ni < 2; ++ni)
#pragma unroll
      for (int r = 0; r < 4; ++r) {
        int row = m0 + wr * 32 + mi * 16 + lg * 4 + r;
        int col = n0 + wc * 32 + ni * 16 + lr;
        C[(size_t)row * Nn + col] = acc[mi][ni][r] + bias[col];
      }
}

// QKV GEMM + fused RMSNorm/RoPE/layout. 128M x 64N tile, 8 waves of 16x64.
__global__ __launch_bounds__(512, 6) void gemm_qkv(
    const u16* __restrict__ A, const u16* __restrict__ W,
    const float* __restrict__ qn_w, const float* __restrict__ kn_w,
    const float2* __restrict__ tab,
    u16* __restrict__ Qb, u16* __restrict__ Kb, u16* __restrict__ Vtb)
{
  __shared__ u16 As[2][128 * 64];   // 16KB
  __shared__ u16 Bs[2][64 * 64];    // 8KB
  const int K = DIM;
  const int t = threadIdx.x;
  const int w = t >> 6, l = t & 63;
  const int lr = l & 15, lg = l >> 4;
  const int m0 = blockIdx.x * 128;
  const int n0 = blockIdx.y * 64;
  f32x4 acc[4] = {};
  const int srow = t >> 3;                      // 0..63
  const int scol = (((t & 7) ^ (srow & 7)) * 8);
  const u16* aSrc = A + (size_t)(m0 + srow) * K + scol;
  const u16* bSrc = W + (size_t)(n0 + srow) * K + scol;
  const size_t r64 = (size_t)64 * K;
  const int sw = lr & 7;
  const int NT = K / 64;

  GLL(aSrc,       &As[0][w * 512]);
  GLL(aSrc + r64, &As[0][4096 + w * 512]);
  GLL(bSrc,       &Bs[0][w * 512]);

  for (int kt = 0; kt < NT; ++kt) {
    const int cur = kt & 1;
    if (kt + 1 < NT) {
      const int k0 = (kt + 1) * 64;
      GLL(aSrc + k0,       &As[cur ^ 1][w * 512]);
      GLL(aSrc + r64 + k0, &As[cur ^ 1][4096 + w * 512]);
      GLL(bSrc + k0,       &Bs[cur ^ 1][w * 512]);
      VM3;
    } else {
      VM0;
    }
    BAR();
#pragma unroll
    for (int kk = 0; kk < 2; ++kk) {
      bf16x8 af = *(const bf16x8*)(&As[cur][0] + (w * 16 + lr) * 64 + (((kk * 4 + lg) ^ sw) * 8));
      bf16x8 bff[4];
#pragma unroll
      for (int ni = 0; ni < 4; ++ni)
        bff[ni] = *(const bf16x8*)(&Bs[cur][0] + (ni * 16 + lr) * 64 + (((kk * 4 + lg) ^ sw) * 8));
#pragma unroll
      for (int ni = 0; ni < 4; ++ni)
        acc[ni] = __builtin_amdgcn_mfma_f32_16x16x32_bf16(af, bff[ni], acc[ni], 0, 0, 0);
    }
    LGKM0;
    BAR();
  }

  // ---- fused epilogue ----
  const int chunk = n0 >> 6;               // 0..35 over [3 types][12 heads]
  const int tt = chunk / 12;               // 0=q 1=k 2=v
  const int h  = chunk % 12;
  const int bB = m0 >> 11;                 // batch (block-const)
  const int bh = bB * NH + h;

  if (tt == 2) {
    const int nbase = (m0 + w * 16 + lg * 4) & 2047;
#pragma unroll
    for (int ni = 0; ni < 4; ++ni) {
      const int d = ni * 16 + lr;
      ushort4 o;
      o.x = f2bf(acc[ni][0]); o.y = f2bf(acc[ni][1]);
      o.z = f2bf(acc[ni][2]); o.w = f2bf(acc[ni][3]);
      *(ushort4*)(Vtb + ((size_t)bh * DH + d) * SEQ + nbase) = o;
    }
  } else {
    const float* wv = (tt == 0 ? qn_w : kn_w);
    const float qs = (tt == 0 ? 0.125f * 1.4426950408889634f : 1.f);
    float wgt[4];
#pragma unroll
    for (int ni = 0; ni < 4; ++ni) wgt[ni] = wv[ni * 16 + lr];
    u16* outp = (tt == 0 ? Qb : Kb) + (size_t)bh * SEQ * DH;
#pragma unroll
    for (int r = 0; r < 4; ++r) {
      float ss = 0.f;
#pragma unroll
      for (int ni = 0; ni < 4; ++ni) ss += acc[ni][r] * acc[ni][r];
      ss += __shfl_xor(ss, 1, 64);
      ss += __shfl_xor(ss, 2, 64);
      ss += __shfl_xor(ss, 4, 64);
      ss += __shfl_xor(ss, 8, 64);
      const float rms = rsqrtf(ss * (1.f / 64.f) + 1e-6f);
      const int trow = m0 + w * 16 + lg * 4 + r;
      const float2* tl = tab + trow * 32;
      u16* rowp = outp + (size_t)(trow & 2047) * DH;
#pragma unroll
      for (int ni = 0; ni < 4; ++ni) {
        const int d = ni * 16 + lr;
        float v = acc[ni][r] * rms * wgt[ni];
        float vp = __shfl_xor(v, 1, 64);
        float2 cssn = tl[ni * 8 + (lr >> 1)];
        float sgn = (d & 1) ? cssn.y : -cssn.y;
        rowp[d] = f2bf((v * cssn.x + vp * sgn) * qs);
      }
    }
  }
}

// Flash attention v5r (best measured): swapped-operand, unshifted exp2
// softmax (scale cancels in o = Pv / P1), counted-vmcnt schedule.
__global__ __launch_bounds__(256, 3) void attn(
    const u16* __restrict__ Qb, const u16* __restrict__ Kb,
    const u16* __restrict__ Vtb, u16* __restrict__ Ob)
{
  __shared__ u16 Ks[2][2][64 * 64];   // [pair dbuf][tile-in-pair]
  __shared__ u16 Vs[2][64 * 64];      // [tile-in-pair]
  const int tid = threadIdx.x;
  const int w = tid >> 6, l = tid & 63;
  const int lr = l & 15, lg = l >> 4;
  const int qg = w & 1, half = w >> 1;
  const int wg = blockIdx.x;
  const int swz = (wg & 7) * 96 + (wg >> 3);   // bijective, 768 % 8 == 0
  const int bh = swz >> 5;
  const int q0 = (swz & 31) * 64;
  const u16* Qp = Qb + (size_t)bh * SEQ * DH;
  const u16* Kp = Kb + (size_t)bh * SEQ * DH;
  const u16* Vp = Vtb + (size_t)bh * DH * SEQ;

  const int qrA = q0 + qg * 32 + lr;
  const bf16x8 bq0a = *(const bf16x8*)(Qp + (size_t)qrA * DH + 8 * lg);
  const bf16x8 bq1a = *(const bf16x8*)(Qp + (size_t)qrA * DH + 32 + 8 * lg);
  const bf16x8 bq0b = *(const bf16x8*)(Qp + (size_t)(qrA + 16) * DH + 8 * lg);
  const bf16x8 bq1b = *(const bf16x8*)(Qp + (size_t)(qrA + 16) * DH + 32 + 8 * lg);

  const int srow = tid >> 3;                  // 0..31
  const int sc16 = (tid & 7) ^ (srow & 7);
  const u16* kSrc = Kp + (size_t)srow * DH + sc16 * 8;    // + kt*4096
  const u16* vSrc = Vp + (size_t)srow * SEQ + sc16 * 8;   // + kt*64

  const int frow = (lr & 3) | ((lr & 4) << 1) | ((lr & 8) >> 1);
  const int ksw = frow & 7;
  const int vsw = lr & 7;

  bf16x8 vone;
#pragma unroll
  for (int j = 0; j < 8; ++j) vone[j] = (short)0x3F80;

  f32x4 oaccA[4] = {}, oaccB[4] = {};
  f32x4 laccA = {}, laccB = {};

  // prologue: K(0); drain; barrier; then V(0), K(1) in flight
  GLL(kSrc,          &Ks[0][0][w * 512]);
  GLL(kSrc + 2048,   &Ks[0][0][w * 512 + 2048]);
  GLL(kSrc + 4096,   &Ks[0][1][w * 512]);
  GLL(kSrc + 6144,   &Ks[0][1][w * 512 + 2048]);
  VM0;
  BAR();
  GLL(vSrc,              &Vs[0][w * 512]);
  GLL(vSrc + 65536,      &Vs[0][w * 512 + 2048]);
  GLL(vSrc + 64,         &Vs[1][w * 512]);
  GLL(vSrc + 64 + 65536, &Vs[1][w * 512 + 2048]);
  GLL(kSrc + 8192,   &Ks[1][0][w * 512]);
  GLL(kSrc + 10240,  &Ks[1][0][w * 512 + 2048]);
  GLL(kSrc + 12288,  &Ks[1][1][w * 512]);
  GLL(kSrc + 14336,  &Ks[1][1][w * 512 + 2048]);

  for (int i = 0; i < 16; ++i) {
    const int p = i & 1;
    const u16* Kt = &Ks[p][half][0];
    const u16* Vt = &Vs[half][0];

    // QK: 16 MFMA (K(i) visible since previous beta)
    f32x4 paccA[4] = {}, paccB[4] = {};
    __builtin_amdgcn_s_setprio(1);
#pragma unroll
    for (int c = 0; c < 4; ++c) {
      const int rbase = (16 * c + frow) * 64;
      bf16x8 ka = *(const bf16x8*)(Kt + rbase + ((lg ^ ksw) * 8));
      bf16x8 kb = *(const bf16x8*)(Kt + rbase + (((4 + lg) ^ ksw) * 8));
      paccA[c] = __builtin_amdgcn_mfma_f32_16x16x32_bf16(ka, bq0a, paccA[c], 0, 0, 0);
      paccA[c] = __builtin_amdgcn_mfma_f32_16x16x32_bf16(kb, bq1a, paccA[c], 0, 0, 0);
      paccB[c] = __builtin_amdgcn_mfma_f32_16x16x32_bf16(ka, bq0b, paccB[c], 0, 0, 0);
      paccB[c] = __builtin_amdgcn_mfma_f32_16x16x32_bf16(kb, bq1b, paccB[c], 0, 0, 0);
    }
    __builtin_amdgcn_s_setprio(0);

    // softmax fully in-register (overlaps V(i)/K(i+1) landing); unshifted exp2
    union { unsigned d[4]; bf16x8 v; } puA[2], puB[2];
#pragma unroll
    for (int g = 0; g < 2; ++g) {
      const int clo = 2 * g, chi = 2 * g + 1;
      float eA[8], eB[8];
#pragma unroll
      for (int r = 0; r < 4; ++r) {
        eA[r]     = __builtin_amdgcn_exp2f(paccA[clo][r]);
        eA[4 + r] = __builtin_amdgcn_exp2f(paccA[chi][r]);
        eB[r]     = __builtin_amdgcn_exp2f(paccB[clo][r]);
        eB[4 + r] = __builtin_amdgcn_exp2f(paccB[chi][r]);
      }
      u32x2 a0 = __builtin_amdgcn_permlane32_swap((unsigned)pkbf(eA[0], eA[1]),
                                                  (unsigned)pkbf(eA[4], eA[5]), false, false);
      u32x2 a1 = __builtin_amdgcn_permlane32_swap((unsigned)pkbf(eA[2], eA[3]),
                                                  (unsigned)pkbf(eA[6], eA[7]), false, false);
      u32x2 b0 = __builtin_amdgcn_permlane32_swap((unsigned)pkbf(eB[0], eB[1]),
                                                  (unsigned)pkbf(eB[4], eB[5]), false, false);
      u32x2 b1 = __builtin_amdgcn_permlane32_swap((unsigned)pkbf(eB[2], eB[3]),
                                                  (unsigned)pkbf(eB[6], eB[7]), false, false);
      puA[g].d[0] = a0[0]; puA[g].d[1] = a1[0]; puA[g].d[2] = a0[1]; puA[g].d[3] = a1[1];
      puB[g].d[0] = b0[0]; puB[g].d[1] = b1[0]; puB[g].d[2] = b0[1]; puB[g].d[3] = b1[1];
    }

    if (i < 15) { VM4; } else { VM0; }   // alpha: V(i) landed, K(i+1) flies on
    BAR();

    // PV: pure MFMA burst
    __builtin_amdgcn_s_setprio(1);
#pragma unroll
    for (int g = 0; g < 2; ++g) {
#pragma unroll
      for (int dt = 0; dt < 4; ++dt) {
        bf16x8 va = *(const bf16x8*)(Vt + (16 * dt + lr) * 64 + (((4 * g + lg) ^ vsw) * 8));
        oaccA[dt] = __builtin_amdgcn_mfma_f32_16x16x32_bf16(va, puA[g].v, oaccA[dt], 0, 0, 0);
        oaccB[dt] = __builtin_amdgcn_mfma_f32_16x16x32_bf16(va, puB[g].v, oaccB[dt], 0, 0, 0);
      }
      laccA = __builtin_amdgcn_mfma_f32_16x16x32_bf16(vone, puA[g].v, laccA, 0, 0, 0);
      laccB = __builtin_amdgcn_mfma_f32_16x16x32_bf16(vone, puB[g].v, laccB, 0, 0, 0);
    }
    __builtin_amdgcn_s_setprio(0);

    LGKM0;  // my LDS reads done
    VM0;    // beta: K(i+1) landed (flight = alpha + PV)
    BAR();  // buffers free + K(i+1) visible block-wide

    if (i + 1 < 16) {   // V(i+1) -> Vs (flight = next QK+softmax)
      const size_t vo = (size_t)(2 * i + 2) * 64;
      GLL(vSrc + vo,              &Vs[0][w * 512]);
      GLL(vSrc + vo + 65536,      &Vs[0][w * 512 + 2048]);
      GLL(vSrc + vo + 64,         &Vs[1][w * 512]);
      GLL(vSrc + vo + 64 + 65536, &Vs[1][w * 512 + 2048]);
    }
    if (i + 2 < 16) {   // K(i+2) -> Ks[p] (just freed)
      const size_t ko = (size_t)(2 * i + 4) * 4096;
      GLL(kSrc + ko,        &Ks[p][0][w * 512]);
      GLL(kSrc + ko + 2048, &Ks[p][0][w * 512 + 2048]);
      GLL(kSrc + ko + 4096, &Ks[p][1][w * 512]);
      GLL(kSrc + ko + 6144, &Ks[p][1][w * 512 + 2048]);
    }
  }

  // combine halves (unshifted partials are directly additive)
  float* scr = (float*)&Ks[0][0][0];
  const int sidA = (qg * 2 + 0) * 64 + l;
  const int sidB = (qg * 2 + 1) * 64 + l;
  if (half == 1) {
#pragma unroll
    for (int dt = 0; dt < 4; ++dt)
#pragma unroll
      for (int r = 0; r < 4; ++r) {
        scr[sidA * 17 + dt * 4 + r] = oaccA[dt][r];
        scr[sidB * 17 + dt * 4 + r] = oaccB[dt][r];
      }
    scr[sidA * 17 + 16] = laccA[0];
    scr[sidB * 17 + 16] = laccB[0];
  }
  __syncthreads();
  if (half == 1) return;
#pragma unroll
  for (int dt = 0; dt < 4; ++dt)
#pragma unroll
    for (int r = 0; r < 4; ++r) {
      oaccA[dt][r] += scr[sidA * 17 + dt * 4 + r];
      oaccB[dt][r] += scr[sidB * 17 + dt * 4 + r];
    }
  const float invA = 1.f / (laccA[0] + scr[sidA * 17 + 16]);
  const float invB = 1.f / (laccB[0] + scr[sidB * 17 + 16]);

  const int b = bh / NH, h = bh % NH;
  const int qA = q0 + qg * 32 + lr;
  size_t obA = (size_t)(b * SEQ + qA) * DIM + h * DH + 4 * lg;
  size_t obB = (size_t)(b * SEQ + qA + 16) * DIM + h * DH + 4 * lg;
#pragma unroll
  for (int dt = 0; dt < 4; ++dt) {
    ushort4 oA, oB;
    oA.x = f2bf(oaccA[dt][0] * invA); oA.y = f2bf(oaccA[dt][1] * invA);
    oA.z = f2bf(oaccA[dt][2] * invA); oA.w = f2bf(oaccA[dt][3] * invA);
    oB.x = f2bf(oaccB[dt][0] * invB); oB.y = f2bf(oaccB[dt][1] * invB);
    oB.z = f2bf(oaccB[dt][2] * invB); oB.w = f2bf(oaccB[dt][3] * invB);
    *(ushort4*)(Ob + obA + 16 * dt) = oA;
    *(ushort4*)(Ob + obB + 16 * dt) = oB;
  }
}

extern "C" void kernel_launch(void* const* d_in, const int* in_sizes, int n_in,
                              void* d_out, int out_size, void* d_ws, size_t ws_size,
                              hipStream_t stream) {
  const float* x      = (const float*)d_in[0];
  const float* pos    = (const float*)d_in[1];
  const float* qkv_w  = (const float*)d_in[2];
  const float* proj_w = (const float*)d_in[3];
  const float* proj_b = (const float*)d_in[4];
  const float* qn_w   = (const float*)d_in[5];
  const float* kn_w   = (const float*)d_in[6];
  char* ws = (char*)d_ws;
  u16*    xb    = (u16*)(ws + 0);          // 6291456
  u16*    wqkv  = (u16*)(ws + 6291456);    // 3538944
  u16*    wproj = (u16*)(ws + 9830400);    // 1179648
  float2* tab   = (float2*)(ws + 11010048);// 1048576
  u16*    Qb    = (u16*)(ws + 12058624);   // 6291456
  u16*    Kb    = (u16*)(ws + 18350080);   // 6291456
  u16*    Vtb   = (u16*)(ws + 24641536);   // 6291456
  u16*    Ob    = (u16*)(ws + 30932992);   // 6291456 -> total 37224448
  float* out = (float*)d_out;

  const int na4 = TOK * DIM / 4, nb4 = QKVN * DIM / 4, nc4 = DIM * DIM / 4;
  const int ntot = na4 + nb4 + nc4 + TOK * 32;
  conv_all<<<(ntot + 255) / 256, 256, 0, stream>>>(
      x, xb, na4, qkv_w, wqkv, nb4, proj_w, wproj, nc4, pos, tab);

  dim3 g1(TOK / 128, QKVN / 64);
  gemm_qkv<<<g1, 512, 0, stream>>>(xb, wqkv, qn_w, kn_w, tab, Qb, Kb, Vtb);

  attn<<<SEQ / 64 * BATCH * NH, 256, 0, stream>>>(Qb, Kb, Vtb, Ob);

  dim3 g3(TOK / 64, DIM / 64);
  gemm64<<<g3, 256, 0, stream>>>(Ob, wproj, out, proj_b, TOK, DIM, DIM);
}

// Round 19
// 86.946 us; speedup vs baseline: 1.1317x; 1.0020x over previous
//
#include <hip/hip_runtime.h>
#include <hip/hip_bf16.h>
#include <math.h>

#define DIM 768
#define NH 12
#define DH 64
#define SEQ 2048
#define BATCH 2
#define TOK (BATCH*SEQ)   // 4096
#define QKVN (3*DIM)      // 2304

typedef __attribute__((ext_vector_type(8))) short bf16x8;
typedef __attribute__((ext_vector_type(4))) float f32x4;
typedef __attribute__((ext_vector_type(2))) unsigned int u32x2;
typedef unsigned short u16;

#define VM0 asm volatile("s_waitcnt vmcnt(0)" ::: "memory")
#define VM3 asm volatile("s_waitcnt vmcnt(3)" ::: "memory")
#define VM4 asm volatile("s_waitcnt vmcnt(4)" ::: "memory")
#define LGKM0 asm volatile("s_waitcnt lgkmcnt(0)" ::: "memory")
#define BAR() __builtin_amdgcn_s_barrier()

__device__ inline u16 f2bf(float f) {
  union { float f; unsigned u; } v; v.f = f;
  unsigned u = v.u;
  u += 0x7fffu + ((u >> 16) & 1u);   // round-to-nearest-even
  return (u16)(u >> 16);
}

__device__ inline int pkbf(float a, float b) {   // packed bf16 pair (RNE)
  __hip_bfloat162 h = __float22bfloat162_rn(make_float2(a, b));
  int r; __builtin_memcpy(&r, &h, 4); return r;
}

// One launch: convert x, qkv_w, proj_w to bf16 AND build the rope cos/sin table.
__global__ void conv_all(const float* __restrict__ a, u16* __restrict__ ao, int na4,
                         const float* __restrict__ b, u16* __restrict__ bo, int nb4,
                         const float* __restrict__ c, u16* __restrict__ co, int nc4,
                         const float* __restrict__ pos, float2* __restrict__ tab) {
  int i4 = blockIdx.x * blockDim.x + threadIdx.x;
  const int nconv = na4 + nb4 + nc4;
  if (i4 < nconv) {
    const float* src; u16* dst; int off;
    if (i4 < na4)            { src = a; dst = ao; off = i4; }
    else if (i4 < na4 + nb4) { src = b; dst = bo; off = i4 - na4; }
    else                     { src = c; dst = co; off = i4 - na4 - nb4; }
    float4 v = ((const float4*)src)[off];
    ushort4 o;
    o.x = f2bf(v.x); o.y = f2bf(v.y); o.z = f2bf(v.z); o.w = f2bf(v.w);
    ((ushort4*)dst)[off] = o;
    return;
  }
  int e = i4 - nconv;                 // rope table: 4096*32 entries
  if (e >= TOK * 32) return;
  int t = e >> 5, p = e & 31;
  float cs = 1.f, sn = 0.f;
  if (p < 30) {
    int axis = p / 10, fi = p % 10;
    float freq = exp2f(-(float)fi * 1.3287712379549449f); // log2(10000)/10
    float ang = pos[t * 3 + axis] * freq;
    cs = cosf(ang); sn = sinf(ang);
  }
  tab[e] = make_float2(cs, sn);
}

#define GLL(g, s) __builtin_amdgcn_global_load_lds((const __attribute__((address_space(1))) void*)(g), (__attribute__((address_space(3))) void*)(s), 16, 0, 0)

// Proj GEMM: C = A * W^T + bias. 64x64 tile, BK=64, XOR-swizzled LDS.
__global__ __launch_bounds__(256, 4) void gemm64(
    const u16* __restrict__ A, const u16* __restrict__ W,
    float* __restrict__ C, const float* __restrict__ bias,
    int M, int Nn, int K)
{
  __shared__ u16 As[2][64 * 64];
  __shared__ u16 Bs[2][64 * 64];
  const int t = threadIdx.x;
  const int w = t >> 6, l = t & 63;
  const int lr = l & 15, lg = l >> 4;
  const int wr = w >> 1, wc = w & 1;
  const int m0 = blockIdx.x * 64;
  const int n0 = blockIdx.y * 64;
  f32x4 acc[2][2] = {};
  const int srow = t >> 3;                      // 0..31
  const int scol = (((t & 7) ^ (srow & 7)) * 8);
  const u16* aSrc = A + (size_t)(m0 + srow) * K + scol;
  const u16* bSrc = W + (size_t)(n0 + srow) * K + scol;
  const size_t r32 = (size_t)32 * K;
  const int sw = lr & 7;
  const int NT = K / 64;

  GLL(aSrc,       &As[0][w * 512]);
  GLL(aSrc + r32, &As[0][2048 + w * 512]);
  GLL(bSrc,       &Bs[0][w * 512]);
  GLL(bSrc + r32, &Bs[0][2048 + w * 512]);

  for (int kt = 0; kt < NT; ++kt) {
    const int cur = kt & 1;
    if (kt + 1 < NT) {
      const int k0 = (kt + 1) * 64;
      GLL(aSrc + k0,       &As[cur ^ 1][w * 512]);
      GLL(aSrc + r32 + k0, &As[cur ^ 1][2048 + w * 512]);
      GLL(bSrc + k0,       &Bs[cur ^ 1][w * 512]);
      GLL(bSrc + r32 + k0, &Bs[cur ^ 1][2048 + w * 512]);
      VM4;
    } else {
      VM0;
    }
    BAR();
#pragma unroll
    for (int kk = 0; kk < 2; ++kk) {
      bf16x8 af[2], bff[2];
#pragma unroll
      for (int mi = 0; mi < 2; ++mi)
        af[mi] = *(const bf16x8*)(&As[cur][0] + (wr * 32 + mi * 16 + lr) * 64 + (((kk * 4 + lg) ^ sw) * 8));
#pragma unroll
      for (int ni = 0; ni < 2; ++ni)
        bff[ni] = *(const bf16x8*)(&Bs[cur][0] + (wc * 32 + ni * 16 + lr) * 64 + (((kk * 4 + lg) ^ sw) * 8));
#pragma unroll
      for (int mi = 0; mi < 2; ++mi)
#pragma unroll
        for (int ni = 0; ni < 2; ++ni)
          acc[mi][ni] = __builtin_amdgcn_mfma_f32_16x16x32_bf16(af[mi], bff[ni], acc[mi][ni], 0, 0, 0);
    }
    LGKM0;
    BAR();
  }

#pragma unroll
  for (int mi = 0; mi < 2; ++mi)
#pragma unroll
    for (int ni = 0; ni < 2; ++ni)
#pragma unroll
      for (int r = 0; r < 4; ++r) {
        int row = m0 + wr * 32 + mi * 16 + lg * 4 + r;
        int col = n0 + wc * 32 + ni * 16 + lr;
        C[(size_t)row * Nn + col] = acc[mi][ni][r] + bias[col];
      }
}

// QKV GEMM + fused RMSNorm/RoPE/layout. 128M x 64N tile, 8 waves of 16x64.
__global__ __launch_bounds__(512, 6) void gemm_qkv(
    const u16* __restrict__ A, const u16* __restrict__ W,
    const float* __restrict__ qn_w, const float* __restrict__ kn_w,
    const float2* __restrict__ tab,
    u16* __restrict__ Qb, u16* __restrict__ Kb, u16* __restrict__ Vtb)
{
  __shared__ u16 As[2][128 * 64];   // 16KB
  __shared__ u16 Bs[2][64 * 64];    // 8KB
  const int K = DIM;
  const int t = threadIdx.x;
  const int w = t >> 6, l = t & 63;
  const int lr = l & 15, lg = l >> 4;
  const int m0 = blockIdx.x * 128;
  const int n0 = blockIdx.y * 64;
  f32x4 acc[4] = {};
  const int srow = t >> 3;                      // 0..63
  const int scol = (((t & 7) ^ (srow & 7)) * 8);
  const u16* aSrc = A + (size_t)(m0 + srow) * K + scol;
  const u16* bSrc = W + (size_t)(n0 + srow) * K + scol;
  const size_t r64 = (size_t)64 * K;
  const int sw = lr & 7;
  const int NT = K / 64;

  GLL(aSrc,       &As[0][w * 512]);
  GLL(aSrc + r64, &As[0][4096 + w * 512]);
  GLL(bSrc,       &Bs[0][w * 512]);

  for (int kt = 0; kt < NT; ++kt) {
    const int cur = kt & 1;
    if (kt + 1 < NT) {
      const int k0 = (kt + 1) * 64;
      GLL(aSrc + k0,       &As[cur ^ 1][w * 512]);
      GLL(aSrc + r64 + k0, &As[cur ^ 1][4096 + w * 512]);
      GLL(bSrc + k0,       &Bs[cur ^ 1][w * 512]);
      VM3;
    } else {
      VM0;
    }
    BAR();
#pragma unroll
    for (int kk = 0; kk < 2; ++kk) {
      bf16x8 af = *(const bf16x8*)(&As[cur][0] + (w * 16 + lr) * 64 + (((kk * 4 + lg) ^ sw) * 8));
      bf16x8 bff[4];
#pragma unroll
      for (int ni = 0; ni < 4; ++ni)
        bff[ni] = *(const bf16x8*)(&Bs[cur][0] + (ni * 16 + lr) * 64 + (((kk * 4 + lg) ^ sw) * 8));
#pragma unroll
      for (int ni = 0; ni < 4; ++ni)
        acc[ni] = __builtin_amdgcn_mfma_f32_16x16x32_bf16(af, bff[ni], acc[ni], 0, 0, 0);
    }
    LGKM0;
    BAR();
  }

  // ---- fused epilogue ----
  const int chunk = n0 >> 6;               // 0..35 over [3 types][12 heads]
  const int tt = chunk / 12;               // 0=q 1=k 2=v
  const int h  = chunk % 12;
  const int bB = m0 >> 11;                 // batch (block-const)
  const int bh = bB * NH + h;

  if (tt == 2) {
    const int nbase = (m0 + w * 16 + lg * 4) & 2047;
#pragma unroll
    for (int ni = 0; ni < 4; ++ni) {
      const int d = ni * 16 + lr;
      ushort4 o;
      o.x = f2bf(acc[ni][0]); o.y = f2bf(acc[ni][1]);
      o.z = f2bf(acc[ni][2]); o.w = f2bf(acc[ni][3]);
      *(ushort4*)(Vtb + ((size_t)bh * DH + d) * SEQ + nbase) = o;
    }
  } else {
    const float* wv = (tt == 0 ? qn_w : kn_w);
    const float qs = (tt == 0 ? 0.125f * 1.4426950408889634f : 1.f);
    float wgt[4];
#pragma unroll
    for (int ni = 0; ni < 4; ++ni) wgt[ni] = wv[ni * 16 + lr];
    u16* outp = (tt == 0 ? Qb : Kb) + (size_t)bh * SEQ * DH;
#pragma unroll
    for (int r = 0; r < 4; ++r) {
      float ss = 0.f;
#pragma unroll
      for (int ni = 0; ni < 4; ++ni) ss += acc[ni][r] * acc[ni][r];
      ss += __shfl_xor(ss, 1, 64);
      ss += __shfl_xor(ss, 2, 64);
      ss += __shfl_xor(ss, 4, 64);
      ss += __shfl_xor(ss, 8, 64);
      const float rms = rsqrtf(ss * (1.f / 64.f) + 1e-6f);
      const int trow = m0 + w * 16 + lg * 4 + r;
      const float2* tl = tab + trow * 32;
      u16* rowp = outp + (size_t)(trow & 2047) * DH;
#pragma unroll
      for (int ni = 0; ni < 4; ++ni) {
        const int d = ni * 16 + lr;
        float v = acc[ni][r] * rms * wgt[ni];
        float vp = __shfl_xor(v, 1, 64);
        float2 cssn = tl[ni * 8 + (lr >> 1)];
        float sgn = (d & 1) ? cssn.y : -cssn.y;
        rowp[d] = f2bf((v * cssn.x + vp * sgn) * qs);
      }
    }
  }
}

// Flash attention v5r (best measured): swapped-operand, unshifted exp2
// softmax (scale cancels in o = Pv / P1), counted-vmcnt schedule.
__global__ __launch_bounds__(256, 3) void attn(
    const u16* __restrict__ Qb, const u16* __restrict__ Kb,
    const u16* __restrict__ Vtb, u16* __restrict__ Ob)
{
  __shared__ u16 Ks[2][2][64 * 64];   // [pair dbuf][tile-in-pair]
  __shared__ u16 Vs[2][64 * 64];      // [tile-in-pair]
  const int tid = threadIdx.x;
  const int w = tid >> 6, l = tid & 63;
  const int lr = l & 15, lg = l >> 4;
  const int qg = w & 1, half = w >> 1;
  const int wg = blockIdx.x;
  const int swz = (wg & 7) * 96 + (wg >> 3);   // bijective, 768 % 8 == 0
  const int bh = swz >> 5;
  const int q0 = (swz & 31) * 64;
  const u16* Qp = Qb + (size_t)bh * SEQ * DH;
  const u16* Kp = Kb + (size_t)bh * SEQ * DH;
  const u16* Vp = Vtb + (size_t)bh * DH * SEQ;

  const int qrA = q0 + qg * 32 + lr;
  const bf16x8 bq0a = *(const bf16x8*)(Qp + (size_t)qrA * DH + 8 * lg);
  const bf16x8 bq1a = *(const bf16x8*)(Qp + (size_t)qrA * DH + 32 + 8 * lg);
  const bf16x8 bq0b = *(const bf16x8*)(Qp + (size_t)(qrA + 16) * DH + 8 * lg);
  const bf16x8 bq1b = *(const bf16x8*)(Qp + (size_t)(qrA + 16) * DH + 32 + 8 * lg);

  const int srow = tid >> 3;                  // 0..31
  const int sc16 = (tid & 7) ^ (srow & 7);
  const u16* kSrc = Kp + (size_t)srow * DH + sc16 * 8;    // + kt*4096
  const u16* vSrc = Vp + (size_t)srow * SEQ + sc16 * 8;   // + kt*64

  const int frow = (lr & 3) | ((lr & 4) << 1) | ((lr & 8) >> 1);
  const int ksw = frow & 7;
  const int vsw = lr & 7;

  bf16x8 vone;
#pragma unroll
  for (int j = 0; j < 8; ++j) vone[j] = (short)0x3F80;

  f32x4 oaccA[4] = {}, oaccB[4] = {};
  f32x4 laccA = {}, laccB = {};

  // prologue: K(0); drain; barrier; then V(0), K(1) in flight
  GLL(kSrc,          &Ks[0][0][w * 512]);
  GLL(kSrc + 2048,   &Ks[0][0][w * 512 + 2048]);
  GLL(kSrc + 4096,   &Ks[0][1][w * 512]);
  GLL(kSrc + 6144,   &Ks[0][1][w * 512 + 2048]);
  VM0;
  BAR();
  GLL(vSrc,              &Vs[0][w * 512]);
  GLL(vSrc + 65536,      &Vs[0][w * 512 + 2048]);
  GLL(vSrc + 64,         &Vs[1][w * 512]);
  GLL(vSrc + 64 + 65536, &Vs[1][w * 512 + 2048]);
  GLL(kSrc + 8192,   &Ks[1][0][w * 512]);
  GLL(kSrc + 10240,  &Ks[1][0][w * 512 + 2048]);
  GLL(kSrc + 12288,  &Ks[1][1][w * 512]);
  GLL(kSrc + 14336,  &Ks[1][1][w * 512 + 2048]);

  for (int i = 0; i < 16; ++i) {
    const int p = i & 1;
    const u16* Kt = &Ks[p][half][0];
    const u16* Vt = &Vs[half][0];

    // QK: 16 MFMA (K(i) visible since previous beta)
    f32x4 paccA[4] = {}, paccB[4] = {};
    __builtin_amdgcn_s_setprio(1);
#pragma unroll
    for (int c = 0; c < 4; ++c) {
      const int rbase = (16 * c + frow) * 64;
      bf16x8 ka = *(const bf16x8*)(Kt + rbase + ((lg ^ ksw) * 8));
      bf16x8 kb = *(const bf16x8*)(Kt + rbase + (((4 + lg) ^ ksw) * 8));
      paccA[c] = __builtin_amdgcn_mfma_f32_16x16x32_bf16(ka, bq0a, paccA[c], 0, 0, 0);
      paccA[c] = __builtin_amdgcn_mfma_f32_16x16x32_bf16(kb, bq1a, paccA[c], 0, 0, 0);
      paccB[c] = __builtin_amdgcn_mfma_f32_16x16x32_bf16(ka, bq0b, paccB[c], 0, 0, 0);
      paccB[c] = __builtin_amdgcn_mfma_f32_16x16x32_bf16(kb, bq1b, paccB[c], 0, 0, 0);
    }
    __builtin_amdgcn_s_setprio(0);

    // softmax fully in-register (overlaps V(i)/K(i+1) landing); unshifted exp2
    union { unsigned d[4]; bf16x8 v; } puA[2], puB[2];
#pragma unroll
    for (int g = 0; g < 2; ++g) {
      const int clo = 2 * g, chi = 2 * g + 1;
      float eA[8], eB[8];
#pragma unroll
      for (int r = 0; r < 4; ++r) {
        eA[r]     = __builtin_amdgcn_exp2f(paccA[clo][r]);
        eA[4 + r] = __builtin_amdgcn_exp2f(paccA[chi][r]);
        eB[r]     = __builtin_amdgcn_exp2f(paccB[clo][r]);
        eB[4 + r] = __builtin_amdgcn_exp2f(paccB[chi][r]);
      }
      u32x2 a0 = __builtin_amdgcn_permlane32_swap((unsigned)pkbf(eA[0], eA[1]),
                                                  (unsigned)pkbf(eA[4], eA[5]), false, false);
      u32x2 a1 = __builtin_amdgcn_permlane32_swap((unsigned)pkbf(eA[2], eA[3]),
                                                  (unsigned)pkbf(eA[6], eA[7]), false, false);
      u32x2 b0 = __builtin_amdgcn_permlane32_swap((unsigned)pkbf(eB[0], eB[1]),
                                                  (unsigned)pkbf(eB[4], eB[5]), false, false);
      u32x2 b1 = __builtin_amdgcn_permlane32_swap((unsigned)pkbf(eB[2], eB[3]),
                                                  (unsigned)pkbf(eB[6], eB[7]), false, false);
      puA[g].d[0] = a0[0]; puA[g].d[1] = a1[0]; puA[g].d[2] = a0[1]; puA[g].d[3] = a1[1];
      puB[g].d[0] = b0[0]; puB[g].d[1] = b1[0]; puB[g].d[2] = b0[1]; puB[g].d[3] = b1[1];
    }

    if (i < 15) { VM4; } else { VM0; }   // alpha: V(i) landed, K(i+1) flies on
    BAR();

    // PV: pure MFMA burst
    __builtin_amdgcn_s_setprio(1);
#pragma unroll
    for (int g = 0; g < 2; ++g) {
#pragma unroll
      for (int dt = 0; dt < 4; ++dt) {
        bf16x8 va = *(const bf16x8*)(Vt + (16 * dt + lr) * 64 + (((4 * g + lg) ^ vsw) * 8));
        oaccA[dt] = __builtin_amdgcn_mfma_f32_16x16x32_bf16(va, puA[g].v, oaccA[dt], 0, 0, 0);
        oaccB[dt] = __builtin_amdgcn_mfma_f32_16x16x32_bf16(va, puB[g].v, oaccB[dt], 0, 0, 0);
      }
      laccA = __builtin_amdgcn_mfma_f32_16x16x32_bf16(vone, puA[g].v, laccA, 0, 0, 0);
      laccB = __builtin_amdgcn_mfma_f32_16x16x32_bf16(vone, puB[g].v, laccB, 0, 0, 0);
    }
    __builtin_amdgcn_s_setprio(0);

    LGKM0;  // my LDS reads done
    VM0;    // beta: K(i+1) landed (flight = alpha + PV)
    BAR();  // buffers free + K(i+1) visible block-wide

    if (i + 1 < 16) {   // V(i+1) -> Vs (flight = next QK+softmax)
      const size_t vo = (size_t)(2 * i + 2) * 64;
      GLL(vSrc + vo,              &Vs[0][w * 512]);
      GLL(vSrc + vo + 65536,      &Vs[0][w * 512 + 2048]);
      GLL(vSrc + vo + 64,         &Vs[1][w * 512]);
      GLL(vSrc + vo + 64 + 65536, &Vs[1][w * 512 + 2048]);
    }
    if (i + 2 < 16) {   // K(i+2) -> Ks[p] (just freed)
      const size_t ko = (size_t)(2 * i + 4) * 4096;
      GLL(kSrc + ko,        &Ks[p][0][w * 512]);
      GLL(kSrc + ko + 2048, &Ks[p][0][w * 512 + 2048]);
      GLL(kSrc + ko + 4096, &Ks[p][1][w * 512]);
      GLL(kSrc + ko + 6144, &Ks[p][1][w * 512 + 2048]);
    }
  }

  // combine halves (unshifted partials are directly additive)
  float* scr = (float*)&Ks[0][0][0];
  const int sidA = (qg * 2 + 0) * 64 + l;
  const int sidB = (qg * 2 + 1) * 64 + l;
  if (half == 1) {
#pragma unroll
    for (int dt = 0; dt < 4; ++dt)
#pragma unroll
      for (int r = 0; r < 4; ++r) {
        scr[sidA * 17 + dt * 4 + r] = oaccA[dt][r];
        scr[sidB * 17 + dt * 4 + r] = oaccB[dt][r];
      }
    scr[sidA * 17 + 16] = laccA[0];
    scr[sidB * 17 + 16] = laccB[0];
  }
  __syncthreads();
  if (half == 1) return;
#pragma unroll
  for (int dt = 0; dt < 4; ++dt)
#pragma unroll
    for (int r = 0; r < 4; ++r) {
      oaccA[dt][r] += scr[sidA * 17 + dt * 4 + r];
      oaccB[dt][r] += scr[sidB * 17 + dt * 4 + r];
    }
  const float invA = 1.f / (laccA[0] + scr[sidA * 17 + 16]);
  const float invB = 1.f / (laccB[0] + scr[sidB * 17 + 16]);

  const int b = bh / NH, h = bh % NH;
  const int qA = q0 + qg * 32 + lr;
  size_t obA = (size_t)(b * SEQ + qA) * DIM + h * DH + 4 * lg;
  size_t obB = (size_t)(b * SEQ + qA + 16) * DIM + h * DH + 4 * lg;
#pragma unroll
  for (int dt = 0; dt < 4; ++dt) {
    ushort4 oA, oB;
    oA.x = f2bf(oaccA[dt][0] * invA); oA.y = f2bf(oaccA[dt][1] * invA);
    oA.z = f2bf(oaccA[dt][2] * invA); oA.w = f2bf(oaccA[dt][3] * invA);
    oB.x = f2bf(oaccB[dt][0] * invB); oB.y = f2bf(oaccB[dt][1] * invB);
    oB.z = f2bf(oaccB[dt][2] * invB); oB.w = f2bf(oaccB[dt][3] * invB);
    *(ushort4*)(Ob + obA + 16 * dt) = oA;
    *(ushort4*)(Ob + obB + 16 * dt) = oB;
  }
}

extern "C" void kernel_launch(void* const* d_in, const int* in_sizes, int n_in,
                              void* d_out, int out_size, void* d_ws, size_t ws_size,
                              hipStream_t stream) {
  const float* x      = (const float*)d_in[0];
  const float* pos    = (const float*)d_in[1];
  const float* qkv_w  = (const float*)d_in[2];
  const float* proj_w = (const float*)d_in[3];
  const float* proj_b = (const float*)d_in[4];
  const float* qn_w   = (const float*)d_in[5];
  const float* kn_w   = (const float*)d_in[6];
  char* ws = (char*)d_ws;
  u16*    xb    = (u16*)(ws + 0);          // 6291456
  u16*    wqkv  = (u16*)(ws + 6291456);    // 3538944
  u16*    wproj = (u16*)(ws + 9830400);    // 1179648
  float2* tab   = (float2*)(ws + 11010048);// 1048576
  u16*    Qb    = (u16*)(ws + 12058624);   // 6291456
  u16*    Kb    = (u16*)(ws + 18350080);   // 6291456
  u16*    Vtb   = (u16*)(ws + 24641536);   // 6291456
  u16*    Ob    = (u16*)(ws + 30932992);   // 6291456 -> total 37224448
  float* out = (float*)d_out;

  const int na4 = TOK * DIM / 4, nb4 = QKVN * DIM / 4, nc4 = DIM * DIM / 4;
  const int ntot = na4 + nb4 + nc4 + TOK * 32;
  conv_all<<<(ntot + 255) / 256, 256, 0, stream>>>(
      x, xb, na4, qkv_w, wqkv, nb4, proj_w, wproj, nc4, pos, tab);

  dim3 g1(TOK / 128, QKVN / 64);
  gemm_qkv<<<g1, 512, 0, stream>>>(xb, wqkv, qn_w, kn_w, tab, Qb, Kb, Vtb);

  attn<<<SEQ / 64 * BATCH * NH, 256, 0, stream>>>(Qb, Kb, Vtb, Ob);

  dim3 g3(TOK / 64, DIM / 64);
  gemm64<<<g3, 256, 0, stream>>>(Ob, wproj, out, proj_b, TOK, DIM, DIM);
}